// Round 12
// baseline (126.243 us; speedup 1.0000x reference)
//
#include <hip/hip_runtime.h>
#include <hip/hip_bf16.h>

#define LOG2E 1.4426950408889634f
#define LN2   0.6931471805599453f

constexpr int Bn = 64, Sn = 512, Hn = 1024, Ln = 9;

typedef __attribute__((ext_vector_type(8))) short short8v;
typedef __attribute__((ext_vector_type(4))) float f32x4;

// intrinsics: pure ops, CSE-able, no operand re-load under remat (R8 lesson)
__device__ __forceinline__ float fexp2(float x) { return __builtin_amdgcn_exp2f(x); }
__device__ __forceinline__ float flog2(float x) { return __builtin_amdgcn_logf(x); }
__device__ __forceinline__ unsigned cvtpk(float lo, float hi) {
    unsigned r; asm("v_cvt_pk_bf16_f32 %0, %1, %2" : "=v"(r) : "v"(lo), "v"(hi)); return r;
}
__device__ __forceinline__ float max9(const float* s) {
    return fmaxf(fmaxf(fmaxf(s[0], s[1]), fmaxf(s[2], s[3])),
                 fmaxf(fmaxf(s[4], s[5]), fmaxf(s[6], fmaxf(s[7], s[8]))));
}

// ================= single fused kernel (R8 structure, intrinsic exp2) =================
// 512 blocks = (b, rb); block computes rows t=64rb..64rb+63 of batch b:
//   barrier-free MFMA emissions (B straight from L2-resident W) -> LDS ->
//   per-wave CL=16 chunk matrix -> Mbuf; release fence + done[b]++;
//   8th arriver stages the batch's 32 matrices and does combine + score + loss.
__global__ __launch_bounds__(256) void fused_kernel(
    const float* __restrict__ hidden, const float* __restrict__ W,
    const float* __restrict__ bias,   const float* __restrict__ st,
    const float* __restrict__ et,     const float* __restrict__ T,
    const int* __restrict__ labels,   const int* __restrict__ mask,
    float* __restrict__ Mbuf, float* __restrict__ eL, float* __restrict__ e0g,
    int* __restrict__ done,   float* __restrict__ out)
{
    __shared__ __align__(16) float e_s[64][12];   // this block's 64x9 emissions
    __shared__ float M_lds[32 * 81];              // last-block combine stage
    __shared__ float part_s[4];
    __shared__ int   sl_sh, last_sh;

    const int tid = threadIdx.x, lane = tid & 63, w = tid >> 6;
    const int bid = blockIdx.x, b = bid >> 3, rb = bid & 7;

    // ---- phase A: MFMA emission tile (16x16x32 bf16) ----
    const int col = lane & 15, g16 = lane >> 4;
    const int row0 = b * Sn + rb * 64 + w * 16;
    const float* hptr = hidden + (size_t)(row0 + col) * Hn + (g16 << 3);
    const float* wptr = W + (size_t)(col < Ln ? col : Ln - 1) * Hn + (g16 << 3);

    f32x4 acc = {0.f, 0.f, 0.f, 0.f};
    #pragma unroll 4
    for (int s = 0; s < 32; ++s) {
        f32x4 a0 = *(const f32x4*)(hptr + s * 32);
        f32x4 a1 = *(const f32x4*)(hptr + s * 32 + 4);
        f32x4 b0 = *(const f32x4*)(wptr + s * 32);
        f32x4 b1 = *(const f32x4*)(wptr + s * 32 + 4);
        uint4 ap, bp;
        ap.x = cvtpk(a0[0], a0[1]); ap.y = cvtpk(a0[2], a0[3]);
        ap.z = cvtpk(a1[0], a1[1]); ap.w = cvtpk(a1[2], a1[3]);
        bp.x = cvtpk(b0[0], b0[1]); bp.y = cvtpk(b0[2], b0[3]);
        bp.z = cvtpk(b1[0], b1[1]); bp.w = cvtpk(b1[2], b1[3]);
        short8v Av = *(short8v*)&ap;
        short8v Bv = *(short8v*)&bp;
        acc = __builtin_amdgcn_mfma_f32_16x16x32_bf16(Av, Bv, acc, 0, 0, 0);
    }

    // ---- tile -> LDS (+bias); labeled emissions -> global ----
    if (col < Ln) {
        const float bv = bias[col];
        #pragma unroll
        for (int r = 0; r < 4; ++r) {
            const int tl = w * 16 + (g16 << 2) + r;       // local t 0..63
            const float v = acc[r] + bv;
            e_s[tl][col] = v;
            const int t = rb * 64 + tl;
            if (col == labels[b * Sn + t]) eL[b * Sn + t] = v;
        }
    }
    if (w == 3) {                                          // sequence length
        const int* mb = mask + b * Sn;
        int s = 0;
        #pragma unroll
        for (int r = 0; r < 8; ++r) s += mb[lane + r * 64];
        #pragma unroll
        for (int off = 32; off; off >>= 1) s += __shfl_xor(s, off);
        if (lane == 0) sl_sh = s;
    }
    __syncthreads();
    const int sl = sl_sh;                                  // >= 128

    if (rb == 0 && tid < Ln) e0g[b * Ln + tid] = e_s[0][tid];

    // ---- phase B: chunk matrix, wave w owns chunk c = 4rb+w ----
    {
        const int c  = (rb << 2) + w;
        const int g0 = max(16 * c, 1);
        const int g1 = min(16 * c + 16, sl);
        if (lane < Ln && g1 > g0) {
            float E[Ln][Ln];
            #pragma unroll
            for (int k = 0; k < Ln; ++k)
                #pragma unroll
                for (int j = 0; j < Ln; ++j)
                    E[k][j] = fexp2(T[k * Ln + j] * LOG2E);
            const int i = lane, l0 = g0 - (rb << 6), nst = g1 - g0;
            float u[Ln];
            {
                const float* ep = e_s[l0];
                #pragma unroll
                for (int j = 0; j < Ln; ++j)
                    u[j] = E[i][j] * fexp2(fmaf(ep[j], LOG2E, -4.f));
            }
            float extra = 0.f;
            for (int s = 1; s < nst; ++s) {
                const float* ep = e_s[l0 + s];
                float q[Ln];
                #pragma unroll
                for (int j = 0; j < Ln; ++j) q[j] = fexp2(fmaf(ep[j], LOG2E, -4.f));
                float v[Ln];
                #pragma unroll
                for (int j = 0; j < Ln; ++j) v[j] = 0.f;
                #pragma unroll
                for (int kk = 0; kk < Ln; ++kk) {
                    const float uk = u[kk];
                    #pragma unroll
                    for (int j = 0; j < Ln; ++j) v[j] = fmaf(uk, E[kk][j], v[j]);
                }
                #pragma unroll
                for (int j = 0; j < Ln; ++j) u[j] = v[j] * q[j];
                if (s == 8) {                              // exponent-range insurance
                    float m = max9(u), iv = 1.f / m;
                    #pragma unroll
                    for (int j = 0; j < Ln; ++j) u[j] *= iv;
                    extra = flog2(m);
                }
            }
            float* o = Mbuf + ((size_t)(b * 32 + c)) * 81 + i * Ln;
            #pragma unroll
            for (int j = 0; j < Ln; ++j)
                o[j] = flog2(u[j]) + extra + 4.f * (float)nst;
        }
    }

    // ---- arrival protocol ----
    __threadfence();                                       // release
    if (tid == 0) last_sh = (atomicAdd(&done[b], 1) == 7);
    __syncthreads();
    if (!last_sh) return;
    __threadfence();                                       // acquire

    // ---- last block of batch b: stage M, combine (w0) || score (w1-3) ----
    {
        const float* src = Mbuf + (size_t)b * 32 * 81;
        for (int i2 = tid; i2 < 32 * 81; i2 += 256) M_lds[i2] = src[i2];
    }
    __syncthreads();

    if (w == 0) {
        const int j9 = lane < Ln ? lane : Ln - 1;
        float al[Ln];
        #pragma unroll
        for (int j = 0; j < Ln; ++j) al[j] = (st[j] + e0g[b * Ln + j]) * LOG2E;
        const int ncb = ((sl - 1) >> 4) + 1;
        for (int c = 0; c < ncb; ++c) {
            const float* mc = &M_lds[c * 81];
            float s[Ln];
            #pragma unroll
            for (int k = 0; k < Ln; ++k) s[k] = al[k] + mc[k * Ln + j9];
            float p = max9(s);
            float sum = fexp2(s[0] - p);
            #pragma unroll
            for (int k = 1; k < Ln; ++k) sum += fexp2(s[k] - p);
            float aj = p + flog2(sum);
            #pragma unroll
            for (int k = 0; k < Ln; ++k) al[k] = __shfl(aj, k);
        }
        float z[Ln];
        #pragma unroll
        for (int j = 0; j < Ln; ++j) z[j] = al[j] + et[j] * LOG2E;
        float p = max9(z);
        float sum = fexp2(z[0] - p);
        #pragma unroll
        for (int j = 1; j < Ln; ++j) sum += fexp2(z[j] - p);
        if (lane == 0) part_s[3] = (p + flog2(sum)) * LN2;   // logZ
    } else {
        const int* lb = labels + b * Sn;
        float sc = 0.f;
        for (int t = (w - 1) * 64 + lane; t < sl; t += 192) {
            sc += eL[b * Sn + t];
            if (t >= 1) sc += T[lb[t - 1] * Ln + lb[t]];
        }
        #pragma unroll
        for (int off = 32; off; off >>= 1) sc += __shfl_xor(sc, off);
        if (w == 1 && lane == 0) sc += st[lb[0]] + et[lb[sl - 1]];
        if (lane == 0) part_s[w - 1] = sc;
    }
    __syncthreads();

    if (tid == 0) {
        float llh = part_s[0] + part_s[1] + part_s[2] - part_s[3];
        atomicAdd(out, llh * (-1.f / 64.f));
    }
}

extern "C" void kernel_launch(void* const* d_in, const int* in_sizes, int n_in,
                              void* d_out, int out_size, void* d_ws, size_t ws_size,
                              hipStream_t stream) {
    const float* hidden = (const float*)d_in[0];
    const float* W      = (const float*)d_in[1];
    const float* bias   = (const float*)d_in[2];
    const float* st     = (const float*)d_in[3];
    const float* et     = (const float*)d_in[4];
    const float* T      = (const float*)d_in[5];
    const int*   labels = (const int*)d_in[6];
    const int*   mask   = (const int*)d_in[7];

    float* Mbuf = (float*)d_ws;                       // 64*32*81 = 165888 floats
    float* eLp  = Mbuf + (size_t)Bn * 32 * 81;        // 64*512
    float* e0g  = eLp + (size_t)Bn * Sn;              // 64*9
    int*   done = (int*)(e0g + Bn * Ln);              // 64 ints
    float* outp = (float*)d_out;

    hipMemsetAsync(done, 0, Bn * sizeof(int), stream);
    hipMemsetAsync(outp, 0, sizeof(float), stream);
    fused_kernel<<<Bn * 8, 256, 0, stream>>>(hidden, W, bias, st, et, T,
                                             labels, mask, Mbuf, eLp, e0g,
                                             done, outp);
}

// Round 13
// 44.259 us; speedup vs baseline: 2.8524x; 2.8524x over previous
//
#include <hip/hip_runtime.h>
#include <hip/hip_bf16.h>

#define LOG2E 1.4426950408889634f
#define LN2   0.6931471805599453f

constexpr int Bn = 64, Sn = 512, Hn = 1024, Ln = 9;
constexpr int CL = 24;                 // crf: emission steps per chunk
constexpr int NC = 22;                 // ceil((Sn-1)/CL)

typedef __attribute__((ext_vector_type(8))) short short8v;
typedef __attribute__((ext_vector_type(4))) float f32x4;

__device__ __forceinline__ float fexp2(float x) { return __builtin_amdgcn_exp2f(x); }
__device__ __forceinline__ float flog2(float x) { return __builtin_amdgcn_logf(x); }
__device__ __forceinline__ unsigned cvtpk(float lo, float hi) {
    unsigned r; asm("v_cvt_pk_bf16_f32 %0, %1, %2" : "=v"(r) : "v"(lo), "v"(hi)); return r;
}
__device__ __forceinline__ float max9(const float* s) {
    return fmaxf(fmaxf(fmaxf(s[0], s[1]), fmaxf(s[2], s[3])),
                 fmaxf(fmaxf(s[4], s[5]), fmaxf(s[6], fmaxf(s[7], s[8]))));
}

// ============ Kernel 1: emissions via bf16 MFMA, LDS-staged contiguous loads ============
// 512 blocks x 256 thr (4 waves x 16 rows). Per k-pass of 128 floats:
//   - wave issues 8 contiguous-1KB float4 loads (2 rows x 512 B each) -> regs
//   - fp32->bf16 convert during ds_write (b64), rows padded to 272 B (2-way banks)
//   - MFMA reads A-frag as ONE ds_read_b128; B-frag from LDS-packed W (R5 scheme)
// Double-buffered, loads for pass p+1 issued before compute of pass p.
__global__ __launch_bounds__(256) void emis_kernel(
    const float* __restrict__ hidden, const float* __restrict__ W,
    const float* __restrict__ bias, float* __restrict__ emis,
    float* __restrict__ out0)
{
    __shared__ __align__(16) unsigned short wfrag[32][64][8];   // 32 KB W B-frags
    __shared__ __align__(16) unsigned short hbuf[2][4][16][136];// 2x4x16x272B = 34 KB

    const int tid = threadIdx.x, lane = tid & 63, w = tid >> 6;
    if (blockIdx.x == 0 && tid == 0) out0[0] = 0.f;   // loss accumulator init

    const int row0 = blockIdx.x * 64 + w * 16;        // this wave's 16 rows
    const char* hbase = (const char*)(hidden + (size_t)row0 * Hn);
    const int srow = lane >> 5;                       // staging: row parity
    const int sbyt = (lane & 31) * 16;                // staging: byte in 512B row-chunk

    // ---- issue pass-0 staging loads, then pack W (overlaps load latency) ----
    f32x4 Lv[8];
    #pragma unroll
    for (int i = 0; i < 8; ++i)
        Lv[i] = *(const f32x4*)(hbase + (size_t)(i * 2 + srow) * 4096 + sbyt);

    for (int f = tid; f < 32 * 64; f += 256) {
        const int s = f >> 6, l = f & 63;
        const int j = l & 15, k0 = s * 32 + ((l >> 4) << 3);
        uint4 pk = {0u, 0u, 0u, 0u};
        if (j < Ln) {
            float4 a = *(const float4*)(W + j * Hn + k0);
            float4 c = *(const float4*)(W + j * Hn + k0 + 4);
            pk.x = cvtpk(a.x, a.y); pk.y = cvtpk(a.z, a.w);
            pk.z = cvtpk(c.x, c.y); pk.w = cvtpk(c.z, c.w);
        }
        *(uint4*)&wfrag[s][l][0] = pk;
    }

    // ---- write pass 0 into buf 0 ----
    #pragma unroll
    for (int i = 0; i < 8; ++i) {
        uint2 pk = { cvtpk(Lv[i][0], Lv[i][1]), cvtpk(Lv[i][2], Lv[i][3]) };
        *(uint2*)&hbuf[0][w][i * 2 + srow][(lane & 31) * 4] = pk;
    }
    __syncthreads();

    const int r16 = lane & 15, g16 = lane >> 4;
    f32x4 acc = {0.f, 0.f, 0.f, 0.f};

    #pragma unroll
    for (int p = 0; p < 8; ++p) {
        const int cur = p & 1;
        if (p < 7) {                                  // issue next pass's loads early
            #pragma unroll
            for (int i = 0; i < 8; ++i)
                Lv[i] = *(const f32x4*)(hbase + (size_t)(i * 2 + srow) * 4096
                                               + (p + 1) * 512 + sbyt);
        }
        #pragma unroll
        for (int s = 0; s < 4; ++s) {                 // 4 MFMA k-steps per pass
            short8v Av = *(const short8v*)&hbuf[cur][w][r16][s * 32 + g16 * 8];
            short8v Bv = *(const short8v*)&wfrag[p * 4 + s][lane][0];
            acc = __builtin_amdgcn_mfma_f32_16x16x32_bf16(Av, Bv, acc, 0, 0, 0);
        }
        if (p < 7) {                                  // convert + write next pass
            #pragma unroll
            for (int i = 0; i < 8; ++i) {
                uint2 pk = { cvtpk(Lv[i][0], Lv[i][1]), cvtpk(Lv[i][2], Lv[i][3]) };
                *(uint2*)&hbuf[cur ^ 1][w][i * 2 + srow][(lane & 31) * 4] = pk;
            }
            __syncthreads();
        }
    }

    const int col = r16;
    if (col < Ln) {
        const float bv = bias[col];
        #pragma unroll
        for (int r = 0; r < 4; ++r) {
            const int row = (g16 << 2) + r;
            emis[(size_t)(row0 + row) * Ln + col] = acc[r] + bv;
        }
    }
}

// ============ Kernel 2: fused CRF (R9 known-good version, verbatim) ============
__global__ __launch_bounds__(256, 1) void crf_kernel(
    const float* __restrict__ emis, const float* __restrict__ st,
    const float* __restrict__ et,   const float* __restrict__ T,
    const int* __restrict__ labels, const int* __restrict__ mask,
    float* __restrict__ out)
{
    __shared__ __align__(16) float e_lds[Sn * Ln];   // raw emissions, 18432 B
    __shared__ float M_lds[NC][Ln][10];              // chunk matrices (log2 domain)
    __shared__ float part[4];
    __shared__ int   sl_sh;

    const int b    = blockIdx.x;
    const int tid  = threadIdx.x;
    const int w    = tid >> 6;
    const int lane = tid & 63;

    // P0: stage emissions + E=exp(T) + sequence length
    {
        const float4* src = (const float4*)(emis + (size_t)b * Sn * Ln);
        float4* dst = (float4*)e_lds;
        for (int i = tid; i < (Sn * Ln) / 4; i += 256) dst[i] = src[i];
    }
    float E[Ln][Ln];
    #pragma unroll
    for (int k = 0; k < Ln; ++k)
        #pragma unroll
        for (int j = 0; j < Ln; ++j)
            E[k][j] = fexp2(T[k * Ln + j] * LOG2E);
    if (w == 3) {
        const int* mb = mask + b * Sn;
        int s = 0;
        #pragma unroll
        for (int r = 0; r < Sn / 64; ++r) s += mb[lane + r * 64];
        #pragma unroll
        for (int off = 32; off; off >>= 1) s += __shfl_xor(s, off);
        if (lane == 0) sl_sh = s;
    }
    __syncthreads();

    const int sl    = sl_sh;                    // >= 128
    const int nreal = (sl - 1 + CL - 1) / CL;

    // P1: chunk transfer matrices (9 lanes/unit, 7 units/wave, 22 units live)
    {
        const int ul = lane / 9;
        const int i  = lane - ul * 9;
        const int c  = w * 7 + ul;
        const int t0 = 1 + c * CL;
        if (ul < 7 && c < nreal) {
            const int nst = min(CL, sl - t0);
            float u[Ln];
            {
                const float* e0 = e_lds + t0 * Ln;
                #pragma unroll
                for (int j = 0; j < Ln; ++j)
                    u[j] = E[i][j] * fexp2(fmaf(e0[j], LOG2E, -4.f));
            }
            float extra = 0.f;
            for (int s = 1; s < nst; ++s) {
                const float* es = e_lds + (t0 + s) * Ln;
                float q[Ln];
                #pragma unroll
                for (int j = 0; j < Ln; ++j)
                    q[j] = fexp2(fmaf(es[j], LOG2E, -4.f));
                float v[Ln];
                #pragma unroll
                for (int j = 0; j < Ln; ++j) v[j] = 0.f;
                #pragma unroll
                for (int kk = 0; kk < Ln; ++kk) {
                    const float uk = u[kk];
                    #pragma unroll
                    for (int j = 0; j < Ln; ++j)
                        v[j] = fmaf(uk, E[kk][j], v[j]);
                }
                #pragma unroll
                for (int j = 0; j < Ln; ++j) u[j] = v[j] * q[j];
                if (s == 12) {                  // exponent-range insurance
                    float m  = max9(u);
                    float iv = 1.f / m;
                    #pragma unroll
                    for (int j = 0; j < Ln; ++j) u[j] *= iv;
                    extra = flog2(m);
                }
            }
            #pragma unroll
            for (int j = 0; j < Ln; ++j)
                M_lds[c][i][j] = flog2(u[j]) + extra + 4.f * (float)nst;
        }
    }
    __syncthreads();

    // P2: wave 0 = combine; waves 1-3 = numerator score
    float logZ = 0.f;
    if (w == 0) {
        const int j9 = lane < Ln ? lane : Ln - 1;
        float al[Ln];
        #pragma unroll
        for (int j = 0; j < Ln; ++j) al[j] = (st[j] + e_lds[j]) * LOG2E;
        for (int c = 0; c < nreal; ++c) {
            float s[Ln];
            #pragma unroll
            for (int k = 0; k < Ln; ++k) s[k] = al[k] + M_lds[c][k][j9];
            float p = max9(s);
            float sum = fexp2(s[0] - p);
            #pragma unroll
            for (int k = 1; k < Ln; ++k) sum += fexp2(s[k] - p);
            float aj = p + flog2(sum);
            #pragma unroll
            for (int k = 0; k < Ln; ++k) al[k] = __shfl(aj, k);
        }
        float z[Ln];
        #pragma unroll
        for (int j = 0; j < Ln; ++j) z[j] = al[j] + et[j] * LOG2E;
        float p = max9(z);
        float sum = fexp2(z[0] - p);
        #pragma unroll
        for (int j = 1; j < Ln; ++j) sum += fexp2(z[j] - p);
        logZ = (p + flog2(sum)) * LN2;
    } else {
        const int* lb = labels + b * Sn;
        float sc = 0.f;
        for (int t = (w - 1) * 64 + lane; t < sl; t += 192) {
            int lt = lb[t];
            sc += e_lds[t * Ln + lt];
            if (t >= 1) sc += T[lb[t - 1] * Ln + lt];
        }
        #pragma unroll
        for (int off = 32; off; off >>= 1) sc += __shfl_xor(sc, off);
        if (w == 1 && lane == 0) sc += st[lb[0]] + et[lb[sl - 1]];
        if (lane == 0) part[w - 1] = sc;
    }
    __syncthreads();

    if (w == 0 && lane == 0) {
        float llh = part[0] + part[1] + part[2] - logZ;
        atomicAdd(out, llh * (-1.f / 64.f));
    }
}

extern "C" void kernel_launch(void* const* d_in, const int* in_sizes, int n_in,
                              void* d_out, int out_size, void* d_ws, size_t ws_size,
                              hipStream_t stream) {
    const float* hidden = (const float*)d_in[0];
    const float* W      = (const float*)d_in[1];
    const float* bias   = (const float*)d_in[2];
    const float* st     = (const float*)d_in[3];
    const float* et     = (const float*)d_in[4];
    const float* T      = (const float*)d_in[5];
    const int*   labels = (const int*)d_in[6];
    const int*   mask   = (const int*)d_in[7];

    float* emis = (float*)d_ws;                 // 32768 * 9 floats
    float* outp = (float*)d_out;

    emis_kernel<<<512, 256, 0, stream>>>(hidden, W, bias, emis, outp);
    crf_kernel<<<Bn, 256, 0, stream>>>(emis, st, et, T, labels, mask, outp);
}